// Round 1
// baseline (257.647 us; speedup 1.0000x reference)
//
#include <hip/hip_runtime.h>
#include <math.h>

// Problem shapes (fixed by setup_inputs):
//   N = 8 rotation bins, Cout = Cin = 128, ks = 5
//   in_H:[8], out_H:[8], weight:[8,128,128,5,5], grid_H:[8] (unused),
//   grid_Rn:[2,5,5], mask:[5,5]
// Output: [128(v=cin-slot), 8(o), 128(u=cout-slot), 8(i), 5, 5] fp32
//   out[v,o,u,i,p,q] = mask[p,q] * bilinear_sample( (1-f)*W[g0,u,v] + f*W[g1,u,v],
//                                                   rot_o(grid_Rn)[p,q] )
// strides: q:1 p:5 i:25 u:200 o:25600 v:204800 ; total 26,214,400 elems.

#define TWO_PI_F 6.28318530717958647692f

__global__ __launch_bounds__(256) void rotconv_weight_kernel(
    const float* __restrict__ in_H,    // [8]
    const float* __restrict__ out_H,   // [8]
    const float* __restrict__ weight,  // [8,128,128,5,5]
    const float* __restrict__ grid_Rn, // [2,5,5] flat: X[25] then Y[25]
    const float* __restrict__ mask,    // [25]
    float* __restrict__ out)
{
    // Each block: 256 threads x 4 elems = 1024 consecutive output elements.
    // 25600 % 1024 == 0  =>  (v, o) are constant within a block.
    const size_t base = (size_t)blockIdx.x * 1024;
    const int v = (int)(base / 204800);
    const int o = (int)((base / 25600) & 7);
    const int r = (int)(base % 25600) + (int)threadIdx.x * 4;  // offset within (v,o) slab

    const float ang = -out_H[o];
    float sthe, cthe;
    sincosf(ang, &sthe, &cthe);

    float res[4];
#pragma unroll
    for (int j = 0; j < 4; ++j) {
        const int e = r + j;             // [0, 25600)
        const int u   = e / 200;
        const int rem = e - u * 200;
        const int i   = rem / 25;
        const int k   = rem - i * 25;    // p*5+q

        const float mk = mask[k];
        if (mk == 0.0f) { res[j] = 0.0f; continue; }

        // ---- rotated sampling coords (depend on o,k) ----
        const float X = grid_Rn[k];
        const float Y = grid_Rn[25 + k];
        const float gx = cthe * X - sthe * Y;
        const float gy = sthe * X + cthe * Y;
        const float x = (gx + 1.0f) * 2.0f;   // * 0.5 * (W-1) with W=5
        const float y = (gy + 1.0f) * 2.0f;
        const float x0f = floorf(x);
        const float y0f = floorf(y);
        const float fx = x - x0f;
        const float fy = y - y0f;
        int x0 = (int)x0f; x0 = x0 < 0 ? 0 : (x0 > 4 ? 4 : x0);
        int y0 = (int)y0f; y0 = y0 < 0 ? 0 : (y0 > 4 ? 4 : y0);
        const int x1 = x0 + 1 > 4 ? 4 : x0 + 1;
        const int y1 = y0 + 1 > 4 ? 4 : y0 + 1;
        const int o00 = y0 * 5 + x0;
        const int o01 = y0 * 5 + x1;
        const int o10 = y1 * 5 + x0;
        const int o11 = y1 * 5 + x1;

        // ---- rotation-bin interpolation (depends on o,i) ----
        const float theta = in_H[i] + ang;          // in_H[i] - out_H[o]
        float m = fmodf(theta, TWO_PI_F);
        if (m < 0.0f) m += TWO_PI_F;
        const float pos  = m * (8.0f / TWO_PI_F);
        const float posf = floorf(pos);
        const float frac = pos - posf;
        const int g0 = ((int)posf) & 7;
        const int g1 = (g0 + 1) & 7;

        // weight[g][u][v][*] tile base: ((g*128 + u)*128 + v)*25
        const float* w0 = weight + (size_t)((g0 * 128 + u) * 128 + v) * 25;
        const float* w1 = weight + (size_t)((g1 * 128 + u) * 128 + v) * 25;

        const float wa = (1.0f - fy) * (1.0f - fx);
        const float wb = (1.0f - fy) * fx;
        const float wc = fy * (1.0f - fx);
        const float wd = fy * fx;

        const float s0 = wa * w0[o00] + wb * w0[o01] + wc * w0[o10] + wd * w0[o11];
        const float s1 = wa * w1[o00] + wb * w1[o01] + wc * w1[o10] + wd * w1[o11];

        res[j] = mk * ((1.0f - frac) * s0 + frac * s1);
    }

    float4 outv = make_float4(res[0], res[1], res[2], res[3]);
    *reinterpret_cast<float4*>(out + base + (size_t)threadIdx.x * 4) = outv;
}

extern "C" void kernel_launch(void* const* d_in, const int* in_sizes, int n_in,
                              void* d_out, int out_size, void* d_ws, size_t ws_size,
                              hipStream_t stream) {
    const float* in_H    = (const float*)d_in[0];
    const float* out_H   = (const float*)d_in[1];
    const float* weight  = (const float*)d_in[2];
    // d_in[3] = grid_H (unused by the forward math)
    const float* grid_Rn = (const float*)d_in[4];
    const float* mask    = (const float*)d_in[5];
    float* out = (float*)d_out;

    // 26,214,400 elements / 1024 per block = 25,600 blocks
    const int total = 128 * 8 * 128 * 8 * 25;
    const int blocks = total / 1024;
    rotconv_weight_kernel<<<dim3(blocks), dim3(256), 0, stream>>>(
        in_H, out_H, weight, grid_Rn, mask, out);
}

// Round 2
// 159.243 us; speedup vs baseline: 1.6180x; 1.6180x over previous
//
#include <hip/hip_runtime.h>
#include <math.h>

// Shapes: N=8, Cout=Cin=128, ks=5.
// Output [v(128), o(8), u(128), i(8), 5, 5] fp32, 26,214,400 elems.
// out[v,o,u,i,p,q] = mask[p,q] * bilinear( (1-frac)*W[g0,u,v,:,:] + frac*W[g1,u,v,:,:],
//                                          rot_o(grid_Rn)[p,q] )
// Block = one (o,i) x 16u x 16v tile:
//   phase 1: stage+blend the two g-tiles into LDS (coalesced float4 global loads)
//   phase 2: each thread emits 25 outputs from 4 LDS taps each.

#define TWO_PI_F 6.28318530717958647692f

__global__ __launch_bounds__(256) void rotconv_weight_kernel(
    const float* __restrict__ in_H,    // [8]
    const float* __restrict__ out_H,   // [8]
    const float* __restrict__ weight,  // [8,128,128,5,5]
    const float* __restrict__ grid_Rn, // [2,5,5]
    const float* __restrict__ mask,    // [25]
    float* __restrict__ out)
{
    __shared__ __align__(16) float s_tile[256 * 25]; // blended tiles, 25.6 KB
    __shared__ int4   s_off[25];                     // tap indices per k
    __shared__ float4 s_w[25];                       // mask-folded bilinear weights

    const int t  = threadIdx.x;
    const int bx = blockIdx.x;
    const int vt = bx & 7;          // v-tile
    const int ut = (bx >> 3) & 7;   // u-tile
    const int i  = (bx >> 6) & 7;
    const int o  = bx >> 9;
    const int u0 = ut * 16;
    const int v0 = vt * 16;

    const float ang = -out_H[o];

    // ---- rotation-bin blend factors (block-uniform) ----
    const float theta = in_H[i] + ang;
    float m = fmodf(theta, TWO_PI_F);
    if (m < 0.0f) m += TWO_PI_F;
    const float pos  = m * (8.0f / TWO_PI_F);
    const float pf   = floorf(pos);
    const float frac = pos - pf;
    const int g0 = ((int)pf) & 7;
    const int g1 = (g0 + 1) & 7;
    const float om = 1.0f - frac;

    // ---- per-k tap coefficients (threads 0..24) ----
    if (t < 25) {
        const int k = t;
        float sthe, cthe;
        sincosf(ang, &sthe, &cthe);
        const float X = grid_Rn[k];
        const float Y = grid_Rn[25 + k];
        const float gx = cthe * X - sthe * Y;
        const float gy = sthe * X + cthe * Y;
        const float x = (gx + 1.0f) * 2.0f;
        const float y = (gy + 1.0f) * 2.0f;
        const float x0f = floorf(x);
        const float y0f = floorf(y);
        const float fx = x - x0f;
        const float fy = y - y0f;
        int x0 = (int)x0f; x0 = x0 < 0 ? 0 : (x0 > 4 ? 4 : x0);
        int y0 = (int)y0f; y0 = y0 < 0 ? 0 : (y0 > 4 ? 4 : y0);
        const int x1 = x0 + 1 > 4 ? 4 : x0 + 1;
        const int y1 = y0 + 1 > 4 ? 4 : y0 + 1;
        const float mk = mask[k];
        s_off[k] = make_int4(y0 * 5 + x0, y0 * 5 + x1, y1 * 5 + x0, y1 * 5 + x1);
        s_w[k] = make_float4(mk * (1.0f - fy) * (1.0f - fx),
                             mk * (1.0f - fy) * fx,
                             mk * fy * (1.0f - fx),
                             mk * fy * fx);
    }

    // ---- phase 1: stage + blend both g-tiles into LDS ----
    // Region per g: 16 chunks (one per uu), each 16v x 25 = 400 contiguous floats.
    // chunk base byte addr is 16B-aligned (12800*… + 1600*vt) -> float4 loads OK.
    const size_t b0 = ((size_t)(g0 * 128 + u0) * 128 + v0) * 25;
    const size_t b1 = ((size_t)(g1 * 128 + u0) * 128 + v0) * 25;
    for (int f4 = t; f4 < 1600; f4 += 256) {         // 1600 float4 = 6400 floats
        const int chunk = f4 / 100;                  // uu
        const int off4  = f4 - chunk * 100;
        const size_t a  = (size_t)chunk * 3200 + (size_t)off4 * 4;
        const float4 a0 = *reinterpret_cast<const float4*>(weight + b0 + a);
        const float4 a1 = *reinterpret_cast<const float4*>(weight + b1 + a);
        float4 bl;
        bl.x = om * a0.x + frac * a1.x;
        bl.y = om * a0.y + frac * a1.y;
        bl.z = om * a0.z + frac * a1.z;
        bl.w = om * a0.w + frac * a1.w;
        *reinterpret_cast<float4*>(s_tile + (size_t)f4 * 4) = bl;
    }

    __syncthreads();

    // ---- phase 2: 25 outputs per thread from 4 LDS taps each ----
    const int uu = t >> 4;
    const int vv = t & 15;
    const float* tp = s_tile + t * 25;   // lane stride 25 (odd) -> 2-way banks only
    const size_t ob = ((((size_t)(v0 + vv) * 8 + o) * 128 + (u0 + uu)) * 8 + i) * 25;

#pragma unroll
    for (int k = 0; k < 25; ++k) {
        const int4   of = s_off[k];   // broadcast
        const float4 w  = s_w[k];     // broadcast
        out[ob + k] = w.x * tp[of.x] + w.y * tp[of.y]
                    + w.z * tp[of.z] + w.w * tp[of.w];
    }
}

extern "C" void kernel_launch(void* const* d_in, const int* in_sizes, int n_in,
                              void* d_out, int out_size, void* d_ws, size_t ws_size,
                              hipStream_t stream) {
    const float* in_H    = (const float*)d_in[0];
    const float* out_H   = (const float*)d_in[1];
    const float* weight  = (const float*)d_in[2];
    // d_in[3] = grid_H (unused)
    const float* grid_Rn = (const float*)d_in[4];
    const float* mask    = (const float*)d_in[5];
    float* out = (float*)d_out;

    // 8 o x 8 i x 8 u-tiles x 8 v-tiles = 4096 blocks
    rotconv_weight_kernel<<<dim3(4096), dim3(256), 0, stream>>>(
        in_H, out_H, weight, grid_Rn, mask, out);
}

// Round 3
// 145.063 us; speedup vs baseline: 1.7761x; 1.0977x over previous
//
#include <hip/hip_runtime.h>
#include <math.h>

// Shapes: N=8, Cout=Cin=128, ks=5.
// Output [v(128), o(8), u(128), i(8), 5, 5] fp32, 26,214,400 elems.
// out[v,o,u,i,p,q] = mask[p,q] * bilinear( (1-frac)*W[g0,u,v,:,:] + frac*W[g1,u,v,:,:],
//                                          rot_o(grid_Rn)[p,q] )
// Block = one (o,i) x 16u x 16v tile.
//   phase 1: stage+blend the two g-tiles into LDS (coalesced float4 loads)
//   phase 2: thread holds FIXED k = t%25 (tap coeffs in registers, x-clamp
//            folded so 4 taps = 2 adjacent-pair LDS reads -> ds_read2_b32),
//            iterates over (u,v) tiles; consecutive lanes write consecutive k
//            -> coalesced stores (the R1 bottleneck: 64 lines/wave-store).

#define TWO_PI_F 6.28318530717958647692f

__global__ __launch_bounds__(256) void rotconv_weight_kernel(
    const float* __restrict__ in_H,    // [8]
    const float* __restrict__ out_H,   // [8]
    const float* __restrict__ weight,  // [8,128,128,5,5]
    const float* __restrict__ grid_Rn, // [2,5,5]
    const float* __restrict__ mask,    // [25]
    float* __restrict__ out)
{
    __shared__ __align__(16) float s_tile[256 * 25]; // blended tiles, 25.6 KB

    const int t  = threadIdx.x;
    const int bx = blockIdx.x;
    const int vt = bx & 7;          // v-tile
    const int ut = (bx >> 3) & 7;   // u-tile
    const int i  = (bx >> 6) & 7;
    const int o  = bx >> 9;
    const int u0 = ut * 16;
    const int v0 = vt * 16;

    const float ang = -out_H[o];

    // ---- rotation-bin blend factors (block-uniform) ----
    const float theta = in_H[i] + ang;
    float m = fmodf(theta, TWO_PI_F);
    if (m < 0.0f) m += TWO_PI_F;
    const float pos  = m * (8.0f / TWO_PI_F);
    const float pf   = floorf(pos);
    const float frac = pos - pf;
    const int g0 = ((int)pf) & 7;
    const int g1 = (g0 + 1) & 7;
    const float om = 1.0f - frac;

    // ---- per-thread FIXED-k tap coefficients (registers) ----
    const int grp = t / 25;          // 0..9 active, 10 = idle tail (t>=250)
    const int k   = t - grp * 25;    // fixed kernel position for this thread
    int rb0, rb1;
    float w00, w01, w10, w11;
    {
        float sthe, cthe;
        sincosf(ang, &sthe, &cthe);
        const float X = grid_Rn[k];
        const float Y = grid_Rn[25 + k];
        const float gx = cthe * X - sthe * Y;
        const float gy = sthe * X + cthe * Y;
        const float x = (gx + 1.0f) * 2.0f;   // * 0.5 * (W-1), W=5
        const float y = (gy + 1.0f) * 2.0f;
        const float x0f = floorf(x);
        const float y0f = floorf(y);
        const float fx = x - x0f;             // ref uses unclamped floor
        const float fy = y - y0f;
        int x0 = (int)x0f; x0 = x0 < 0 ? 0 : (x0 > 4 ? 4 : x0);
        int y0 = (int)y0f; y0 = y0 < 0 ? 0 : (y0 > 4 ? 4 : y0);
        const int y1 = y0 + 1 > 4 ? 4 : y0 + 1;
        const float mk = mask[k];
        float wa = mk * (1.0f - fy) * (1.0f - fx);
        float wb = mk * (1.0f - fy) * fx;
        float wc = mk * fy * (1.0f - fx);
        float wd = mk * fy * fx;
        // fold the x-clamp (x1==x0==4) into pair weights so taps are always
        // the adjacent pair (xb, xb+1):
        int xb = x0;
        if (x0 == 4) { xb = 3; wb += wa; wa = 0.0f; wd += wc; wc = 0.0f; }
        rb0 = y0 * 5 + xb;
        rb1 = y1 * 5 + xb;
        w00 = wa; w01 = wb; w10 = wc; w11 = wd;
    }

    // ---- phase 1: stage + blend both g-tiles into LDS ----
    // 16 chunks (one per uu), each 16v x 25 = 400 contiguous floats;
    // chunk base is 16B-aligned (v0 multiple of 16 -> base = 1600*Y bytes).
    const size_t b0 = ((size_t)(g0 * 128 + u0) * 128 + v0) * 25;
    const size_t b1 = ((size_t)(g1 * 128 + u0) * 128 + v0) * 25;
    for (int f4 = t; f4 < 1600; f4 += 256) {         // 1600 float4 = 6400 floats
        const int chunk = f4 / 100;                  // uu
        const int off4  = f4 - chunk * 100;
        const size_t a  = (size_t)chunk * 3200 + (size_t)off4 * 4;
        const float4 a0 = *reinterpret_cast<const float4*>(weight + b0 + a);
        const float4 a1 = *reinterpret_cast<const float4*>(weight + b1 + a);
        float4 bl;
        bl.x = om * a0.x + frac * a1.x;
        bl.y = om * a0.y + frac * a1.y;
        bl.z = om * a0.z + frac * a1.z;
        bl.w = om * a0.w + frac * a1.w;
        *reinterpret_cast<float4*>(s_tile + (size_t)f4 * 4) = bl;
    }

    __syncthreads();

    // ---- phase 2: fixed-k thread sweeps (u,v) tiles; coalesced stores ----
    // out addr = obase + vv*204800 + uu*200  (k folded into obase);
    // consecutive lanes = consecutive k = consecutive dwords.
    const size_t obase = ((((size_t)v0 * 8 + o) * 128 + u0) * 8 + i) * 25 + k;
    if (grp < 10) {
#pragma unroll 4
        for (int run = grp; run < 256; run += 10) {
            const int uu = run >> 4;
            const int vv = run & 15;
            const float* tp = s_tile + run * 25;
            const float v00 = tp[rb0];
            const float v01 = tp[rb0 + 1];
            const float v10 = tp[rb1];
            const float v11 = tp[rb1 + 1];
            out[obase + (size_t)vv * 204800 + (size_t)uu * 200] =
                w00 * v00 + w01 * v01 + w10 * v10 + w11 * v11;
        }
    }
}

extern "C" void kernel_launch(void* const* d_in, const int* in_sizes, int n_in,
                              void* d_out, int out_size, void* d_ws, size_t ws_size,
                              hipStream_t stream) {
    const float* in_H    = (const float*)d_in[0];
    const float* out_H   = (const float*)d_in[1];
    const float* weight  = (const float*)d_in[2];
    // d_in[3] = grid_H (unused)
    const float* grid_Rn = (const float*)d_in[4];
    const float* mask    = (const float*)d_in[5];
    float* out = (float*)d_out;

    // 8 o x 8 i x 8 u-tiles x 8 v-tiles = 4096 blocks
    rotconv_weight_kernel<<<dim3(4096), dim3(256), 0, stream>>>(
        in_H, out_H, weight, grid_Rn, mask, out);
}